// Round 6
// baseline (105.308 us; speedup 1.0000x reference)
//
#include <hip/hip_runtime.h>

// Problem constants (from reference): B=32, L=4096, D=128, N=5, V=128
constexpr int Bn = 32;
constexpr int Ln = 4096;
constexpr int Dn = 128;
constexpr int Vn = 128;
constexpr int N1 = 4;  // N - 1 context slots

// Kernel A: T'[k*128+t][v] = dot(emb[t], W[v, k*D:(k+1)*D]) (+ bias[v] for k==0)
// 512 blocks (one per (k,t)) x 256 threads = 4 waves; each wave owns 32 v's.
// Lanes span f (coalesced 512B reads of each W row); 64-lane shuffle reduction.
__global__ void __launch_bounds__(256)
build_table_kernel(const float* __restrict__ emb,
                   const float* __restrict__ W,
                   const float* __restrict__ bias,
                   float* __restrict__ T) {
    const int kt   = blockIdx.x;        // k*128 + t
    const int k    = kt >> 7;
    const int t    = kt & 127;
    const int wave = threadIdx.x >> 6;  // 0..3
    const int lane = threadIdx.x & 63;

    // lane l holds emb[t][2l], emb[t][2l+1]
    const float2 e2 = *(const float2*)(emb + t * Dn + lane * 2);

    for (int vp = 0; vp < 32; ++vp) {
        const int v = (wave << 5) | vp;
        const float2 w2 = *(const float2*)(W + (size_t)v * (Dn * N1) + k * Dn + lane * 2);
        float p = w2.x * e2.x + w2.y * e2.y;
#pragma unroll
        for (int m = 1; m < 64; m <<= 1)
            p += __shfl_xor(p, m, 64);
        if (lane == 0)
            T[kt * Vn + v] = p + (k == 0 ? bias[v] : 0.f);  // fold bias into slot 0
    }
}

// Kernel B: out[b,j,v] = sum_k T'[k][x[b,j-4+k]][v]  (bias folded into T'[0]);
// j<4 rows are bias-only. Each thread: 4 consecutive positions x one float4 of v.
// Regular (cache-allocating) stores: 64 MiB output fits in the 256 MiB LLC, so
// stores retire at L2/LLC instead of waiting on HBM drain (vs nt stores).
__global__ void __launch_bounds__(256)
ngram_logits_kernel(const int* __restrict__ x,
                    const float* __restrict__ T,
                    const float* __restrict__ bias,
                    float* __restrict__ out) {
    const int tid     = blockIdx.x * blockDim.x + threadIdx.x;
    const int vq      = tid & 31;          // v / 4
    const int g       = tid >> 5;          // position group
    const int basepos = g << 2;            // first of 4 positions (4-aligned)
    const int j0      = basepos & (Ln - 1);

    float4* outq = (float4*)out;

    if (j0 == 0) {
        // positions j=0..3 of a batch row: bias-only
        const float4 bv = ((const float4*)bias)[vq];
#pragma unroll
        for (int i = 0; i < 4; ++i)
            outq[(size_t)(basepos + i) * 32 + vq] = bv;
        return;
    }

    // token window w[0..6] = x[basepos-4 .. basepos+2]; both int4 loads 16B-aligned
    const int4 xa = *(const int4*)(x + basepos - 4);
    const int4 xb = *(const int4*)(x + basepos);
    int w[7] = {xa.x, xa.y, xa.z, xa.w, xb.x, xb.y, xb.z};

    const float4* Tq = (const float4*)T;  // [4][128][32] float4
    float4 acc[4];
#pragma unroll
    for (int i = 0; i < 4; ++i) {
        float4 a = Tq[(size_t)(0 * Vn + w[i + 0]) * 32 + vq];
#pragma unroll
        for (int k = 1; k < N1; ++k) {
            const float4 tk = Tq[(size_t)(k * Vn + w[i + k]) * 32 + vq];
            a.x += tk.x; a.y += tk.y; a.z += tk.z; a.w += tk.w;
        }
        acc[i] = a;
    }

#pragma unroll
    for (int i = 0; i < 4; ++i)
        outq[(size_t)(basepos + i) * 32 + vq] = acc[i];
}

extern "C" void kernel_launch(void* const* d_in, const int* in_sizes, int n_in,
                              void* d_out, int out_size, void* d_ws, size_t ws_size,
                              hipStream_t stream) {
    const int*   x    = (const int*)d_in[0];    // (B, L) int32
    const float* emb  = (const float*)d_in[1];  // (V, D) fp32
    const float* W    = (const float*)d_in[2];  // (V, D*(N-1)) fp32
    const float* bias = (const float*)d_in[3];  // (V,) fp32
    float*       out  = (float*)d_out;          // (B, L, V) fp32
    float*       T    = (float*)d_ws;           // (4,128,128) fp32 = 256 KiB

    build_table_kernel<<<N1 * Vn, 256, 0, stream>>>(emb, W, bias, T);

    const int total_threads = (Bn * Ln / 4) * (Vn / 4);  // 1,048,576
    const int block = 256;
    ngram_logits_kernel<<<total_threads / block, block, 0, stream>>>(x, T, bias, out);
}

// Round 7
// 92.320 us; speedup vs baseline: 1.1407x; 1.1407x over previous
//
#include <hip/hip_runtime.h>

// Problem constants (from reference): B=32, L=4096, D=128, N=5, V=128
constexpr int Bn = 32;
constexpr int Ln = 4096;
constexpr int Dn = 128;
constexpr int Vn = 128;
constexpr int N1 = 4;  // N - 1 context slots

typedef float vfloat4 __attribute__((ext_vector_type(4)));  // native vec for nontemporal builtins

// Kernel A: build T[k][t][v] = dot(emb[t], W[v, k*D : (k+1)*D]) (+ bias[v] for k==0)
// grid: 4*128 = 512 blocks (one per (k,t)), block: 128 threads (one per v)
// NOTE (R4/R6 evidence): coalesced/transposed and shuffle-reduce variants of this
// kernel measured neutral-to-worse end-to-end; this uncoalesced form is latency-
// hidden well enough at 512 blocks. Keep.
__global__ void build_table_kernel(const float* __restrict__ emb,
                                   const float* __restrict__ W,
                                   const float* __restrict__ bias,
                                   float* __restrict__ T) {
    const int kt = blockIdx.x;        // k*128 + t
    const int k  = kt >> 7;
    const int t  = kt & 127;
    const int v  = threadIdx.x;       // 0..127

    __shared__ float4 e[Dn / 4];
    if (threadIdx.x < Dn / 4) {
        e[threadIdx.x] = ((const float4*)(emb + t * Dn))[threadIdx.x];
    }
    __syncthreads();

    const float4* w = (const float4*)(W + (size_t)v * (Dn * N1) + k * Dn);
    float acc = (k == 0) ? bias[v] : 0.f;  // fold bias into slot-0 table
#pragma unroll
    for (int i = 0; i < Dn / 4; ++i) {
        float4 wv = w[i];
        float4 ev = e[i];
        acc += wv.x * ev.x + wv.y * ev.y + wv.z * ev.z + wv.w * ev.w;
    }
    T[(size_t)kt * Vn + v] = acc;
}

// Kernel B: out[b,j,v] = sum_k T'[k][x[b,j-4+k]][v]  (bias folded into T'[0]);
// j<4 rows are bias-only. Each thread computes 4 consecutive positions x one
// float4 of v. Nontemporal stores (R6 evidence: regular stores regressed).
__global__ void __launch_bounds__(256)
ngram_logits_kernel(const int* __restrict__ x,
                    const float* __restrict__ T,
                    const float* __restrict__ bias,
                    float* __restrict__ out) {
    const int tid     = blockIdx.x * blockDim.x + threadIdx.x;
    const int vq      = tid & 31;          // v / 4
    const int g       = tid >> 5;          // position group
    const int basepos = g << 2;            // first of 4 positions (4-aligned)
    const int j0      = basepos & (Ln - 1);

    vfloat4* outq = (vfloat4*)out;

    if (j0 == 0) {
        // positions j=0..3: bias-only rows
        const vfloat4 bv = ((const vfloat4*)bias)[vq];
#pragma unroll
        for (int i = 0; i < 4; ++i)
            __builtin_nontemporal_store(bv, &outq[(size_t)(basepos + i) * 32 + vq]);
        return;
    }

    // token window w[0..6] = x[basepos-4 .. basepos+2]; both int4 loads 16B-aligned
    const int4 xa = *(const int4*)(x + basepos - 4);
    const int4 xb = *(const int4*)(x + basepos);
    int w[7] = {xa.x, xa.y, xa.z, xa.w, xb.x, xb.y, xb.z};

    const vfloat4* Tq = (const vfloat4*)T;  // [4][128][32] vfloat4
    vfloat4 acc[4];
#pragma unroll
    for (int i = 0; i < 4; ++i) {
        vfloat4 a = Tq[(size_t)(0 * Vn + w[i + 0]) * 32 + vq];
#pragma unroll
        for (int k = 1; k < N1; ++k) {
            a += Tq[(size_t)(k * Vn + w[i + k]) * 32 + vq];
        }
        acc[i] = a;
    }

#pragma unroll
    for (int i = 0; i < 4; ++i)
        __builtin_nontemporal_store(acc[i], &outq[(size_t)(basepos + i) * 32 + vq]);
}

extern "C" void kernel_launch(void* const* d_in, const int* in_sizes, int n_in,
                              void* d_out, int out_size, void* d_ws, size_t ws_size,
                              hipStream_t stream) {
    const int*   x    = (const int*)d_in[0];    // (B, L) int32
    const float* emb  = (const float*)d_in[1];  // (V, D) fp32
    const float* W    = (const float*)d_in[2];  // (V, D*(N-1)) fp32
    const float* bias = (const float*)d_in[3];  // (V,) fp32
    float*       out  = (float*)d_out;          // (B, L, V) fp32
    float*       T    = (float*)d_ws;           // (4, 128, 128) fp32 = 256 KiB

    build_table_kernel<<<N1 * Vn, Vn, 0, stream>>>(emb, W, bias, T);

    const int total_threads = (Bn * Ln / 4) * (Vn / 4);  // 1,048,576
    const int block = 256;
    ngram_logits_kernel<<<total_threads / block, block, 0, stream>>>(x, T, bias, out);
}